// Round 1
// baseline (841.478 us; speedup 1.0000x reference)
//
#include <hip/hip_runtime.h>
#include <hip/hip_bf16.h>
#include <math.h>

typedef __bf16 BF16;
typedef __attribute__((ext_vector_type(8))) __bf16 bf16x8;
typedef __attribute__((ext_vector_type(4))) float f32x4;

__device__ __forceinline__ void gld_lds16(const void* g, void* l) {
    __builtin_amdgcn_global_load_lds(
        (__attribute__((address_space(1))) void*)(const void*)g,
        (__attribute__((address_space(3))) void*)l, 16, 0, 0);
}

// ---------------- LayerNorm (fp32 in -> bf16 out), row = 2048 ----------------
__global__ __launch_bounds__(256) void lnorm(const float* __restrict__ x,
                                             const float* __restrict__ w,
                                             BF16* __restrict__ out) {
    const int row = blockIdx.x, tid = threadIdx.x;
    const float* xr = x + (size_t)row * 2048;
    float4 a = *(const float4*)(xr + tid * 8);
    float4 b = *(const float4*)(xr + tid * 8 + 4);
    float s1 = a.x + a.y + a.z + a.w + b.x + b.y + b.z + b.w;
    float s2 = a.x*a.x + a.y*a.y + a.z*a.z + a.w*a.w +
               b.x*b.x + b.y*b.y + b.z*b.z + b.w*b.w;
    #pragma unroll
    for (int off = 32; off; off >>= 1) {
        s1 += __shfl_xor(s1, off);
        s2 += __shfl_xor(s2, off);
    }
    __shared__ float red[8];
    const int l = tid & 63, wv = tid >> 6;
    if (l == 0) { red[wv] = s1; red[4 + wv] = s2; }
    __syncthreads();
    s1 = red[0] + red[1] + red[2] + red[3];
    s2 = red[4] + red[5] + red[6] + red[7];
    const float mean = s1 * (1.0f / 2048.0f);
    const float var  = s2 * (1.0f / 2048.0f) - mean * mean;
    const float rstd = rsqrtf(var + 1e-5f);
    float4 wa = *(const float4*)(w + tid * 8);
    float4 wb = *(const float4*)(w + tid * 8 + 4);
    bf16x8 o;
    o[0] = (BF16)((a.x - mean) * rstd * wa.x);
    o[1] = (BF16)((a.y - mean) * rstd * wa.y);
    o[2] = (BF16)((a.z - mean) * rstd * wa.z);
    o[3] = (BF16)((a.w - mean) * rstd * wa.w);
    o[4] = (BF16)((b.x - mean) * rstd * wb.x);
    o[5] = (BF16)((b.y - mean) * rstd * wb.y);
    o[6] = (BF16)((b.z - mean) * rstd * wb.z);
    o[7] = (BF16)((b.w - mean) * rstd * wb.w);
    *(bf16x8*)(out + (size_t)row * 2048 + tid * 8) = o;
}

// ------------- fp32 [K][N] -> bf16 [N][K] transposed convert -----------------
__global__ __launch_bounds__(256) void wtrans(const float* __restrict__ W,
                                              BF16* __restrict__ Wt,
                                              int K, int N) {
    __shared__ BF16 tile[32][33];
    const int n0 = blockIdx.x * 32, k0 = blockIdx.y * 32;
    const int tx = threadIdx.x, ty = threadIdx.y;
    #pragma unroll
    for (int i = 0; i < 4; i++)
        tile[ty + 8 * i][tx] = (BF16)W[(size_t)(k0 + ty + 8 * i) * N + n0 + tx];
    __syncthreads();
    #pragma unroll
    for (int i = 0; i < 4; i++)
        Wt[(size_t)(n0 + ty + 8 * i) * K + k0 + tx] = tile[tx][ty + 8 * i];
}

// --------- V slice of qkv (bf16 [B,T,3C]) -> vT bf16 [B*H][128][2048] ---------
__global__ __launch_bounds__(256) void vtrans(const BF16* __restrict__ qkv,
                                              BF16* __restrict__ vT) {
    __shared__ BF16 tile[32][33];
    const int t0 = blockIdx.x * 32, d0 = blockIdx.y * 32, bh = blockIdx.z;
    const int b = bh >> 4, h = bh & 15;
    const int tx = threadIdx.x, ty = threadIdx.y;
    const BF16* src = qkv + (size_t)b * 2048 * 6144 + 4096 + h * 128;
    #pragma unroll
    for (int i = 0; i < 4; i++)
        tile[ty + 8 * i][tx] = src[(size_t)(t0 + ty + 8 * i) * 6144 + d0 + tx];
    __syncthreads();
    BF16* dst = vT + (size_t)bh * 128 * 2048;
    #pragma unroll
    for (int i = 0; i < 4; i++)
        dst[(size_t)(d0 + ty + 8 * i) * 2048 + t0 + tx] = tile[tx][ty + 8 * i];
}

// --------------- GEMM: C[M][N] = A[M][K] * Bt[N][K]^T (bf16 MFMA) ------------
// MODE 0: store bf16. MODE 1: gelu -> bf16. MODE 2: fp32 out = resid + acc.
template <int MODE>
__global__ __launch_bounds__(256) void gemm_bt(const BF16* __restrict__ A,
                                               const BF16* __restrict__ Bt,
                                               void* __restrict__ out,
                                               const float* __restrict__ resid,
                                               int M, int N, int K) {
    __shared__ BF16 As[128 * 32];
    __shared__ BF16 Bs[128 * 32];
    const int tid = threadIdx.x;
    const int l = tid & 63, w = tid >> 6;
    const int wm = w >> 1, wn = w & 1;
    const int g = l >> 4, c = l & 15;
    const int m0 = blockIdx.y * 128, n0 = blockIdx.x * 128;

    f32x4 acc[4][4] = {};

    const int rowA = tid >> 2;         // 0..63
    const int col8 = (tid & 3) * 8;    // 0,8,16,24
    const BF16* gA = A + (size_t)(m0 + rowA) * K + col8;
    const BF16* gB = Bt + (size_t)(n0 + rowA) * K + col8;
    BF16* lA = &As[w * 512];
    BF16* lB = &Bs[w * 512];

    const int nk = K >> 5;
    for (int kt = 0; kt < nk; ++kt) {
        if (kt) __syncthreads();
        gld_lds16(gA, lA);
        gld_lds16(gA + (size_t)64 * K, lA + 2048);
        gld_lds16(gB, lB);
        gld_lds16(gB + (size_t)64 * K, lB + 2048);
        gA += 32; gB += 32;
        __syncthreads();

        bf16x8 af[4], bfr[4];
        #pragma unroll
        for (int i = 0; i < 4; i++)
            af[i] = *(const bf16x8*)&As[(wm * 64 + i * 16 + c) * 32 + g * 8];
        #pragma unroll
        for (int i = 0; i < 4; i++)
            bfr[i] = *(const bf16x8*)&Bs[(wn * 64 + i * 16 + c) * 32 + g * 8];
        #pragma unroll
        for (int mi = 0; mi < 4; mi++)
            #pragma unroll
            for (int ni = 0; ni < 4; ni++)
                acc[mi][ni] = __builtin_amdgcn_mfma_f32_16x16x32_bf16(
                    af[mi], bfr[ni], acc[mi][ni], 0, 0, 0);
    }

    #pragma unroll
    for (int mi = 0; mi < 4; mi++)
        #pragma unroll
        for (int ni = 0; ni < 4; ni++)
            #pragma unroll
            for (int j = 0; j < 4; j++) {
                const int row = m0 + wm * 64 + mi * 16 + g * 4 + j;
                const int col = n0 + wn * 64 + ni * 16 + c;
                const float v = acc[mi][ni][j];
                const size_t idx = (size_t)row * N + col;
                if (MODE == 0) {
                    ((BF16*)out)[idx] = (BF16)v;
                } else if (MODE == 1) {
                    // new_gelu(v) == v * sigmoid(2*sqrt(2/pi)*(v + 0.044715 v^3))
                    const float t = v + 0.044715f * v * v * v;
                    const float s = 1.0f / (1.0f + __expf(-1.5957691216057308f * t));
                    ((BF16*)out)[idx] = (BF16)(v * s);
                } else {
                    ((float*)out)[idx] = resid[idx] + v;
                }
            }
}

// ------------------------- causal flash attention ----------------------------
// grid (T/64, B*H), 4 waves; wave handles 16 q rows. KBLK=32, D=128.
__global__ __launch_bounds__(256) void attn(const BF16* __restrict__ qkv,
                                            const BF16* __restrict__ vT,
                                            const float* __restrict__ x,
                                            float* __restrict__ x2) {
    __shared__ BF16 Ks[32 * 128];
    __shared__ BF16 Vs[128 * 32];
    __shared__ BF16 Ps[4][16 * 32];
    const int tid = threadIdx.x, l = tid & 63, w = tid >> 6;
    const int g = l >> 4, c = l & 15;
    const int qb = blockIdx.x, bh = blockIdx.y;
    const int b = bh >> 4, h = bh & 15;
    const int q0 = qb * 64;

    const BF16* qbase = qkv + (size_t)b * 2048 * 6144 + h * 128;
    const BF16* kbase = qbase + 2048;
    const BF16* vbase = vT + (size_t)bh * 128 * 2048;

    bf16x8 qf[4];
    {
        const BF16* qrow = qbase + (size_t)(q0 + w * 16 + c) * 6144 + g * 8;
        #pragma unroll
        for (int kc = 0; kc < 4; kc++) qf[kc] = *(const bf16x8*)(qrow + kc * 32);
    }

    float m[4]    = {-1e30f, -1e30f, -1e30f, -1e30f};
    float lsum[4] = {0.f, 0.f, 0.f, 0.f};
    f32x4 O[8] = {};
    const float scale = 0.08838834764831845f;  // 1/sqrt(128)

    const int rowK = tid >> 4;        // 0..15
    const int colK = (tid & 15) * 8;
    const int rowV = tid >> 2;        // 0..63
    const int colV = (tid & 3) * 8;

    const int nkt = (q0 >> 5) + 2;
    for (int kt = 0; kt < nkt; ++kt) {
        const int k0 = kt * 32;
        __syncthreads();
        gld_lds16(kbase + (size_t)(k0 + rowK) * 6144 + colK, &Ks[w * 512]);
        gld_lds16(kbase + (size_t)(k0 + 16 + rowK) * 6144 + colK, &Ks[2048 + w * 512]);
        gld_lds16(vbase + (size_t)rowV * 2048 + k0 + colV, &Vs[w * 512]);
        gld_lds16(vbase + (size_t)(64 + rowV) * 2048 + k0 + colV, &Vs[2048 + w * 512]);
        __syncthreads();

        // S = Q K^T for 2 key sub-tiles of 16
        f32x4 s[2] = {};
        #pragma unroll
        for (int ni = 0; ni < 2; ni++)
            #pragma unroll
            for (int kc = 0; kc < 4; kc++) {
                bf16x8 kf = *(const bf16x8*)&Ks[(ni * 16 + c) * 128 + kc * 32 + g * 8];
                s[ni] = __builtin_amdgcn_mfma_f32_16x16x32_bf16(qf[kc], kf, s[ni], 0, 0, 0);
            }

        float sv[2][4];
        #pragma unroll
        for (int ni = 0; ni < 2; ni++)
            #pragma unroll
            for (int j = 0; j < 4; j++) {
                const int key = k0 + ni * 16 + c;
                const int qi  = q0 + w * 16 + g * 4 + j;
                sv[ni][j] = (key <= qi) ? s[ni][j] * scale : -1e30f;
            }

        float sf[4];
        #pragma unroll
        for (int j = 0; j < 4; j++) {
            float tm = fmaxf(sv[0][j], sv[1][j]);
            tm = fmaxf(tm, __shfl_xor(tm, 1));
            tm = fmaxf(tm, __shfl_xor(tm, 2));
            tm = fmaxf(tm, __shfl_xor(tm, 4));
            tm = fmaxf(tm, __shfl_xor(tm, 8));
            const float mn = fmaxf(m[j], tm);
            sf[j] = __expf(m[j] - mn);
            m[j] = mn;
        }

        float rs[4] = {0.f, 0.f, 0.f, 0.f};
        #pragma unroll
        for (int ni = 0; ni < 2; ni++)
            #pragma unroll
            for (int j = 0; j < 4; j++) {
                const float p = __expf(sv[ni][j] - m[j]);
                rs[j] += p;
                Ps[w][(g * 4 + j) * 32 + ni * 16 + c] = (BF16)p;
            }
        #pragma unroll
        for (int j = 0; j < 4; j++) {
            float t = rs[j];
            t += __shfl_xor(t, 1);
            t += __shfl_xor(t, 2);
            t += __shfl_xor(t, 4);
            t += __shfl_xor(t, 8);
            lsum[j] = lsum[j] * sf[j] + t;
        }
        #pragma unroll
        for (int dn = 0; dn < 8; dn++)
            #pragma unroll
            for (int j = 0; j < 4; j++) O[dn][j] *= sf[j];

        bf16x8 pf = *(const bf16x8*)&Ps[w][c * 32 + g * 8];
        #pragma unroll
        for (int dn = 0; dn < 8; dn++) {
            bf16x8 vf = *(const bf16x8*)&Vs[(dn * 16 + c) * 32 + g * 8];
            O[dn] = __builtin_amdgcn_mfma_f32_16x16x32_bf16(pf, vf, O[dn], 0, 0, 0);
        }
    }

    float inv[4];
    #pragma unroll
    for (int j = 0; j < 4; j++) inv[j] = 1.0f / lsum[j];
    #pragma unroll
    for (int dn = 0; dn < 8; dn++)
        #pragma unroll
        for (int j = 0; j < 4; j++) {
            const int t   = q0 + w * 16 + g * 4 + j;
            const int col = h * 128 + dn * 16 + c;
            const size_t idx = ((size_t)b * 2048 + t) * 2048 + col;
            x2[idx] = x[idx] + O[dn][j] * inv[j];
        }
}

// -----------------------------------------------------------------------------
extern "C" void kernel_launch(void* const* d_in, const int* in_sizes, int n_in,
                              void* d_out, int out_size, void* d_ws, size_t ws_size,
                              hipStream_t stream) {
    const float* x     = (const float*)d_in[0];
    const float* w_qkv = (const float*)d_in[1];
    const float* w1    = (const float*)d_in[2];
    const float* w2    = (const float*)d_in[3];
    const float* ln_w  = (const float*)d_in[4];
    float* out = (float*)d_out;

    char* ws = (char*)d_ws;
    BF16* h_buf = (BF16*)ws;  ws += (size_t)4096 * 2048 * 2;   // 16.8 MB
    BF16* qkvb  = (BF16*)ws;  ws += (size_t)4096 * 6144 * 2;   // 50.3 MB
    BF16* vTb   = (BF16*)ws;  ws += (size_t)32 * 128 * 2048 * 2; // 16.8 MB
    BF16* wqkvT = (BF16*)ws;  ws += (size_t)6144 * 2048 * 2;   // 25.2 MB
    BF16* w1T   = (BF16*)ws;  ws += (size_t)8192 * 2048 * 2;   // 33.6 MB
    BF16* w2T   = (BF16*)ws;  ws += (size_t)2048 * 8192 * 2;   // 33.6 MB
    BF16* mlp1  = (BF16*)ws;  ws += (size_t)4096 * 8192 * 2;   // 67.1 MB

    // ---- attention branch ----
    lnorm<<<4096, 256, 0, stream>>>(x, ln_w, h_buf);
    wtrans<<<dim3(192, 64), dim3(32, 8), 0, stream>>>(w_qkv, wqkvT, 2048, 6144);
    gemm_bt<0><<<dim3(48, 32), 256, 0, stream>>>(h_buf, wqkvT, qkvb, nullptr,
                                                 4096, 6144, 2048);
    vtrans<<<dim3(64, 4, 32), dim3(32, 8), 0, stream>>>(qkvb, vTb);
    attn<<<dim3(32, 32), 256, 0, stream>>>(qkvb, vTb, x, out);  // out = x2

    // ---- MLP branch ----
    lnorm<<<4096, 256, 0, stream>>>(out, ln_w, h_buf);
    wtrans<<<dim3(256, 64), dim3(32, 8), 0, stream>>>(w1, w1T, 2048, 8192);
    gemm_bt<1><<<dim3(64, 32), 256, 0, stream>>>(h_buf, w1T, mlp1, nullptr,
                                                 4096, 8192, 2048);
    wtrans<<<dim3(64, 256), dim3(32, 8), 0, stream>>>(w2, w2T, 8192, 2048);
    gemm_bt<2><<<dim3(16, 32), 256, 0, stream>>>(mlp1, w2T, out, out,
                                                 4096, 2048, 8192);
}

// Round 2
// 740.181 us; speedup vs baseline: 1.1369x; 1.1369x over previous
//
#include <hip/hip_runtime.h>
#include <hip/hip_bf16.h>
#include <math.h>

typedef __bf16 BF16;
typedef __attribute__((ext_vector_type(8))) __bf16 bf16x8;
typedef __attribute__((ext_vector_type(4))) float f32x4;

__device__ __forceinline__ void gld_lds16(const void* g, void* l) {
    __builtin_amdgcn_global_load_lds(
        (__attribute__((address_space(1))) void*)(const void*)g,
        (__attribute__((address_space(3))) void*)l, 16, 0, 0);
}

// ---------------- LayerNorm (fp32 in -> bf16 out), row = 2048 ----------------
__global__ __launch_bounds__(256) void lnorm(const float* __restrict__ x,
                                             const float* __restrict__ w,
                                             BF16* __restrict__ out) {
    const int row = blockIdx.x, tid = threadIdx.x;
    const float* xr = x + (size_t)row * 2048;
    float4 a = *(const float4*)(xr + tid * 8);
    float4 b = *(const float4*)(xr + tid * 8 + 4);
    float s1 = a.x + a.y + a.z + a.w + b.x + b.y + b.z + b.w;
    float s2 = a.x*a.x + a.y*a.y + a.z*a.z + a.w*a.w +
               b.x*b.x + b.y*b.y + b.z*b.z + b.w*b.w;
    #pragma unroll
    for (int off = 32; off; off >>= 1) {
        s1 += __shfl_xor(s1, off);
        s2 += __shfl_xor(s2, off);
    }
    __shared__ float red[8];
    const int l = tid & 63, wv = tid >> 6;
    if (l == 0) { red[wv] = s1; red[4 + wv] = s2; }
    __syncthreads();
    s1 = red[0] + red[1] + red[2] + red[3];
    s2 = red[4] + red[5] + red[6] + red[7];
    const float mean = s1 * (1.0f / 2048.0f);
    const float var  = s2 * (1.0f / 2048.0f) - mean * mean;
    const float rstd = rsqrtf(var + 1e-5f);
    float4 wa = *(const float4*)(w + tid * 8);
    float4 wb = *(const float4*)(w + tid * 8 + 4);
    bf16x8 o;
    o[0] = (BF16)((a.x - mean) * rstd * wa.x);
    o[1] = (BF16)((a.y - mean) * rstd * wa.y);
    o[2] = (BF16)((a.z - mean) * rstd * wa.z);
    o[3] = (BF16)((a.w - mean) * rstd * wa.w);
    o[4] = (BF16)((b.x - mean) * rstd * wb.x);
    o[5] = (BF16)((b.y - mean) * rstd * wb.y);
    o[6] = (BF16)((b.z - mean) * rstd * wb.z);
    o[7] = (BF16)((b.w - mean) * rstd * wb.w);
    *(bf16x8*)(out + (size_t)row * 2048 + tid * 8) = o;
}

// ------------- fp32 [K][N] -> bf16 [N][K] transposed convert -----------------
__global__ __launch_bounds__(256) void wtrans(const float* __restrict__ W,
                                              BF16* __restrict__ Wt,
                                              int K, int N) {
    __shared__ BF16 tile[32][33];
    const int n0 = blockIdx.x * 32, k0 = blockIdx.y * 32;
    const int tx = threadIdx.x, ty = threadIdx.y;
    #pragma unroll
    for (int i = 0; i < 4; i++)
        tile[ty + 8 * i][tx] = (BF16)W[(size_t)(k0 + ty + 8 * i) * N + n0 + tx];
    __syncthreads();
    #pragma unroll
    for (int i = 0; i < 4; i++)
        Wt[(size_t)(n0 + ty + 8 * i) * K + k0 + tx] = tile[tx][ty + 8 * i];
}

// --------- V slice of qkv (bf16 [B,T,3C]) -> vT bf16 [B*H][128][2048] ---------
__global__ __launch_bounds__(256) void vtrans(const BF16* __restrict__ qkv,
                                              BF16* __restrict__ vT) {
    __shared__ BF16 tile[32][33];
    const int t0 = blockIdx.x * 32, d0 = blockIdx.y * 32, bh = blockIdx.z;
    const int b = bh >> 4, h = bh & 15;
    const int tx = threadIdx.x, ty = threadIdx.y;
    const BF16* src = qkv + (size_t)b * 2048 * 6144 + 4096 + h * 128;
    #pragma unroll
    for (int i = 0; i < 4; i++)
        tile[ty + 8 * i][tx] = src[(size_t)(t0 + ty + 8 * i) * 6144 + d0 + tx];
    __syncthreads();
    BF16* dst = vT + (size_t)bh * 128 * 2048;
    #pragma unroll
    for (int i = 0; i < 4; i++)
        dst[(size_t)(d0 + ty + 8 * i) * 2048 + t0 + tx] = tile[tx][ty + 8 * i];
}

// --------------- GEMM: C[M][N] = A[M][K] * Bt[N][K]^T (bf16 MFMA) ------------
// MODE 0: store bf16. MODE 1: gelu -> bf16. MODE 2: fp32 out = resid + acc.
template <int MODE>
__global__ __launch_bounds__(256) void gemm_bt(const BF16* __restrict__ A,
                                               const BF16* __restrict__ Bt,
                                               void* __restrict__ out,
                                               const float* __restrict__ resid,
                                               int M, int N, int K) {
    __shared__ BF16 As[128 * 32];
    __shared__ BF16 Bs[128 * 32];
    const int tid = threadIdx.x;
    const int l = tid & 63, w = tid >> 6;
    const int wm = w >> 1, wn = w & 1;
    const int g = l >> 4, c = l & 15;
    const int m0 = blockIdx.y * 128, n0 = blockIdx.x * 128;

    f32x4 acc[4][4] = {};

    const int rowA = tid >> 2;         // 0..63
    const int col8 = (tid & 3) * 8;    // 0,8,16,24
    const BF16* gA = A + (size_t)(m0 + rowA) * K + col8;
    const BF16* gB = Bt + (size_t)(n0 + rowA) * K + col8;
    BF16* lA = &As[w * 512];
    BF16* lB = &Bs[w * 512];

    const int nk = K >> 5;
    for (int kt = 0; kt < nk; ++kt) {
        if (kt) __syncthreads();
        gld_lds16(gA, lA);
        gld_lds16(gA + (size_t)64 * K, lA + 2048);
        gld_lds16(gB, lB);
        gld_lds16(gB + (size_t)64 * K, lB + 2048);
        gA += 32; gB += 32;
        __syncthreads();

        bf16x8 af[4], bfr[4];
        #pragma unroll
        for (int i = 0; i < 4; i++)
            af[i] = *(const bf16x8*)&As[(wm * 64 + i * 16 + c) * 32 + g * 8];
        #pragma unroll
        for (int i = 0; i < 4; i++)
            bfr[i] = *(const bf16x8*)&Bs[(wn * 64 + i * 16 + c) * 32 + g * 8];
        #pragma unroll
        for (int mi = 0; mi < 4; mi++)
            #pragma unroll
            for (int ni = 0; ni < 4; ni++)
                acc[mi][ni] = __builtin_amdgcn_mfma_f32_16x16x32_bf16(
                    af[mi], bfr[ni], acc[mi][ni], 0, 0, 0);
    }

    #pragma unroll
    for (int mi = 0; mi < 4; mi++)
        #pragma unroll
        for (int ni = 0; ni < 4; ni++)
            #pragma unroll
            for (int j = 0; j < 4; j++) {
                const int row = m0 + wm * 64 + mi * 16 + g * 4 + j;
                const int col = n0 + wn * 64 + ni * 16 + c;
                const float v = acc[mi][ni][j];
                const size_t idx = (size_t)row * N + col;
                if (MODE == 0) {
                    ((BF16*)out)[idx] = (BF16)v;
                } else if (MODE == 1) {
                    // new_gelu(v) == v * sigmoid(2*sqrt(2/pi)*(v + 0.044715 v^3))
                    const float t = v + 0.044715f * v * v * v;
                    const float s = 1.0f / (1.0f + __expf(-1.5957691216057308f * t));
                    ((BF16*)out)[idx] = (BF16)(v * s);
                } else {
                    ((float*)out)[idx] = resid[idx] + v;
                }
            }
}

// ------------------------- causal flash attention ----------------------------
// grid (32, B*H), 4 waves, QBLK=64 (16 q rows/wave), KBLK=64, D=128.
// K/V staged via global_load_lds with inverse-XOR-swizzled global source
// (linear LDS dest); reads apply byte ^= ((row&7)<<4)  ->  ~2-way conflicts.
// qb reversed so heavy causal blocks dispatch first.
__global__ __launch_bounds__(256) void attn(const BF16* __restrict__ qkv,
                                            const BF16* __restrict__ vT,
                                            const float* __restrict__ x,
                                            float* __restrict__ x2) {
    __shared__ BF16 Ks[64 * 128];      // [key][d]   row = 256 B, swizzled
    __shared__ BF16 Vs[128 * 64];      // [d][key]   row = 128 B, swizzled
    __shared__ BF16 Ps[4][16 * 72];    // per-wave P [q][key], pad 64->72
    const int tid = threadIdx.x, l = tid & 63, w = tid >> 6;
    const int g = l >> 4, c = l & 15;
    const int qb = 31 - (int)blockIdx.x, bh = blockIdx.y;
    const int b = bh >> 4, h = bh & 15;
    const int q0 = qb * 64;
    const int xr = (c & 7) << 4;       // read-side XOR (row = *16 + c)

    const BF16* qbase = qkv + (size_t)b * 2048 * 6144 + h * 128;
    const char* kbase = (const char*)(qbase + 2048);
    const char* vbase = (const char*)(vT + (size_t)bh * 128 * 2048);

    bf16x8 qf[4];
    {
        const BF16* qrow = qbase + (size_t)(q0 + w * 16 + c) * 6144 + g * 8;
        #pragma unroll
        for (int kc = 0; kc < 4; kc++) qf[kc] = *(const bf16x8*)(qrow + kc * 32);
    }

    float m[4]    = {-1e30f, -1e30f, -1e30f, -1e30f};
    float lsum[4] = {0.f, 0.f, 0.f, 0.f};
    f32x4 O[8] = {};
    const float scale = 0.08838834764831845f;  // 1/sqrt(128)

    for (int kt = 0; kt <= qb; ++kt) {
        const int k0 = kt * 64;
        __syncthreads();
        #pragma unroll
        for (int s = 0; s < 4; ++s) {
            // K: linear LDS slot (w*4+s)*1024B + lane*16; row = 256B
            const int rK = (w * 4 + s) * 4 + (l >> 4);
            const int cK = ((l & 15) * 16) ^ ((rK & 7) << 4);
            gld_lds16(kbase + (size_t)(k0 + rK) * 12288 + cK,
                      &Ks[(w * 4 + s) * 512]);
            // V: row = 128B
            const int rV = (w * 4 + s) * 8 + (l >> 3);
            const int cV = ((l & 7) * 16) ^ ((rV & 7) << 4);
            gld_lds16(vbase + (size_t)rV * 4096 + (size_t)k0 * 2 + cV,
                      &Vs[(w * 4 + s) * 512]);
        }
        __syncthreads();

        // ---- S = Q K^T : 4 key sub-tiles of 16 ----
        f32x4 s4[4] = {};
        #pragma unroll
        for (int ni = 0; ni < 4; ni++)
            #pragma unroll
            for (int kc = 0; kc < 4; kc++) {
                const bf16x8 kf = *(const bf16x8*)((const char*)Ks +
                    (ni * 16 + c) * 256 + ((kc * 64 + g * 16) ^ xr));
                s4[ni] = __builtin_amdgcn_mfma_f32_16x16x32_bf16(
                    qf[kc], kf, s4[ni], 0, 0, 0);
            }

        const bool maskt = (kt == qb);
        float sv[4][4];
        #pragma unroll
        for (int ni = 0; ni < 4; ni++)
            #pragma unroll
            for (int j = 0; j < 4; j++) {
                const float v = s4[ni][j] * scale;
                sv[ni][j] = (!maskt || (ni * 16 + c <= w * 16 + g * 4 + j))
                          ? v : -1e30f;
            }

        float sf[4];
        #pragma unroll
        for (int j = 0; j < 4; j++) {
            float tm = fmaxf(fmaxf(sv[0][j], sv[1][j]), fmaxf(sv[2][j], sv[3][j]));
            tm = fmaxf(tm, __shfl_xor(tm, 1));
            tm = fmaxf(tm, __shfl_xor(tm, 2));
            tm = fmaxf(tm, __shfl_xor(tm, 4));
            tm = fmaxf(tm, __shfl_xor(tm, 8));
            const float mn = fmaxf(m[j], tm);
            sf[j] = __expf(m[j] - mn);
            m[j] = mn;
        }

        float rs[4] = {0.f, 0.f, 0.f, 0.f};
        #pragma unroll
        for (int ni = 0; ni < 4; ni++)
            #pragma unroll
            for (int j = 0; j < 4; j++) {
                const float p = __expf(sv[ni][j] - m[j]);
                rs[j] += p;
                Ps[w][(g * 4 + j) * 72 + ni * 16 + c] = (BF16)p;
            }
        #pragma unroll
        for (int j = 0; j < 4; j++) {
            float t = rs[j];
            t += __shfl_xor(t, 1);
            t += __shfl_xor(t, 2);
            t += __shfl_xor(t, 4);
            t += __shfl_xor(t, 8);
            lsum[j] = lsum[j] * sf[j] + t;
        }
        #pragma unroll
        for (int dn = 0; dn < 8; dn++)
            #pragma unroll
            for (int j = 0; j < 4; j++) O[dn][j] *= sf[j];

        // ---- O += P V ----
        bf16x8 pa[2];
        #pragma unroll
        for (int ks = 0; ks < 2; ks++)
            pa[ks] = *(const bf16x8*)((const char*)Ps[w] +
                         c * 144 + ks * 64 + g * 16);
        #pragma unroll
        for (int dn = 0; dn < 8; dn++)
            #pragma unroll
            for (int ks = 0; ks < 2; ks++) {
                const bf16x8 vf = *(const bf16x8*)((const char*)Vs +
                    (dn * 16 + c) * 128 + ((ks * 64 + g * 16) ^ xr));
                O[dn] = __builtin_amdgcn_mfma_f32_16x16x32_bf16(
                    pa[ks], vf, O[dn], 0, 0, 0);
            }
    }

    float inv[4];
    #pragma unroll
    for (int j = 0; j < 4; j++) inv[j] = 1.0f / lsum[j];
    #pragma unroll
    for (int dn = 0; dn < 8; dn++)
        #pragma unroll
        for (int j = 0; j < 4; j++) {
            const int t   = q0 + w * 16 + g * 4 + j;
            const int col = h * 128 + dn * 16 + c;
            const size_t idx = ((size_t)b * 2048 + t) * 2048 + col;
            x2[idx] = x[idx] + O[dn][j] * inv[j];
        }
}

// -----------------------------------------------------------------------------
extern "C" void kernel_launch(void* const* d_in, const int* in_sizes, int n_in,
                              void* d_out, int out_size, void* d_ws, size_t ws_size,
                              hipStream_t stream) {
    const float* x     = (const float*)d_in[0];
    const float* w_qkv = (const float*)d_in[1];
    const float* w1    = (const float*)d_in[2];
    const float* w2    = (const float*)d_in[3];
    const float* ln_w  = (const float*)d_in[4];
    float* out = (float*)d_out;

    char* ws = (char*)d_ws;
    BF16* h_buf = (BF16*)ws;  ws += (size_t)4096 * 2048 * 2;   // 16.8 MB
    BF16* qkvb  = (BF16*)ws;  ws += (size_t)4096 * 6144 * 2;   // 50.3 MB
    BF16* vTb   = (BF16*)ws;  ws += (size_t)32 * 128 * 2048 * 2; // 16.8 MB
    BF16* wqkvT = (BF16*)ws;  ws += (size_t)6144 * 2048 * 2;   // 25.2 MB
    BF16* w1T   = (BF16*)ws;  ws += (size_t)8192 * 2048 * 2;   // 33.6 MB
    BF16* w2T   = (BF16*)ws;  ws += (size_t)2048 * 8192 * 2;   // 33.6 MB
    BF16* mlp1  = (BF16*)ws;  ws += (size_t)4096 * 8192 * 2;   // 67.1 MB

    // ---- attention branch ----
    lnorm<<<4096, 256, 0, stream>>>(x, ln_w, h_buf);
    wtrans<<<dim3(192, 64), dim3(32, 8), 0, stream>>>(w_qkv, wqkvT, 2048, 6144);
    gemm_bt<0><<<dim3(48, 32), 256, 0, stream>>>(h_buf, wqkvT, qkvb, nullptr,
                                                 4096, 6144, 2048);
    vtrans<<<dim3(64, 4, 32), dim3(32, 8), 0, stream>>>(qkvb, vTb);
    attn<<<dim3(32, 32), 256, 0, stream>>>(qkvb, vTb, x, out);  // out = x2

    // ---- MLP branch ----
    lnorm<<<4096, 256, 0, stream>>>(out, ln_w, h_buf);
    wtrans<<<dim3(256, 64), dim3(32, 8), 0, stream>>>(w1, w1T, 2048, 8192);
    gemm_bt<1><<<dim3(64, 32), 256, 0, stream>>>(h_buf, w1T, mlp1, nullptr,
                                                 4096, 8192, 2048);
    wtrans<<<dim3(64, 256), dim3(32, 8), 0, stream>>>(w2, w2T, 8192, 2048);
    gemm_bt<2><<<dim3(16, 32), 256, 0, stream>>>(mlp1, w2T, out, out,
                                                 4096, 2048, 8192);
}

// Round 3
// 644.102 us; speedup vs baseline: 1.3064x; 1.1492x over previous
//
#include <hip/hip_runtime.h>
#include <hip/hip_bf16.h>
#include <math.h>

typedef __bf16 BF16;
typedef __attribute__((ext_vector_type(8))) __bf16 bf16x8;
typedef __attribute__((ext_vector_type(4))) float f32x4;

__device__ __forceinline__ void gld_lds16(const void* g, void* l) {
    __builtin_amdgcn_global_load_lds(
        (__attribute__((address_space(1))) void*)(const void*)g,
        (__attribute__((address_space(3))) void*)l, 16, 0, 0);
}

template <int N> __device__ __forceinline__ void vmwait() {
    if constexpr (N == 0) asm volatile("s_waitcnt vmcnt(0)" ::: "memory");
    else if constexpr (N == 2) asm volatile("s_waitcnt vmcnt(2)" ::: "memory");
    else if constexpr (N == 3) asm volatile("s_waitcnt vmcnt(3)" ::: "memory");
    else if constexpr (N == 4) asm volatile("s_waitcnt vmcnt(4)" ::: "memory");
    else if constexpr (N == 6) asm volatile("s_waitcnt vmcnt(6)" ::: "memory");
    else if constexpr (N == 8) asm volatile("s_waitcnt vmcnt(8)" ::: "memory");
}

__device__ __forceinline__ void barrier_() {
    asm volatile("" ::: "memory");
    __builtin_amdgcn_s_barrier();
    asm volatile("" ::: "memory");
}

// ---------------- LayerNorm (fp32 in -> bf16 out), row = 2048 ----------------
__global__ __launch_bounds__(256) void lnorm(const float* __restrict__ x,
                                             const float* __restrict__ w,
                                             BF16* __restrict__ out) {
    const int row = blockIdx.x, tid = threadIdx.x;
    const float* xr = x + (size_t)row * 2048;
    float4 a = *(const float4*)(xr + tid * 8);
    float4 b = *(const float4*)(xr + tid * 8 + 4);
    float s1 = a.x + a.y + a.z + a.w + b.x + b.y + b.z + b.w;
    float s2 = a.x*a.x + a.y*a.y + a.z*a.z + a.w*a.w +
               b.x*b.x + b.y*b.y + b.z*b.z + b.w*b.w;
    #pragma unroll
    for (int off = 32; off; off >>= 1) {
        s1 += __shfl_xor(s1, off);
        s2 += __shfl_xor(s2, off);
    }
    __shared__ float red[8];
    const int l = tid & 63, wv = tid >> 6;
    if (l == 0) { red[wv] = s1; red[4 + wv] = s2; }
    __syncthreads();
    s1 = red[0] + red[1] + red[2] + red[3];
    s2 = red[4] + red[5] + red[6] + red[7];
    const float mean = s1 * (1.0f / 2048.0f);
    const float var  = s2 * (1.0f / 2048.0f) - mean * mean;
    const float rstd = rsqrtf(var + 1e-5f);
    float4 wa = *(const float4*)(w + tid * 8);
    float4 wb = *(const float4*)(w + tid * 8 + 4);
    bf16x8 o;
    o[0] = (BF16)((a.x - mean) * rstd * wa.x);
    o[1] = (BF16)((a.y - mean) * rstd * wa.y);
    o[2] = (BF16)((a.z - mean) * rstd * wa.z);
    o[3] = (BF16)((a.w - mean) * rstd * wa.w);
    o[4] = (BF16)((b.x - mean) * rstd * wb.x);
    o[5] = (BF16)((b.y - mean) * rstd * wb.y);
    o[6] = (BF16)((b.z - mean) * rstd * wb.z);
    o[7] = (BF16)((b.w - mean) * rstd * wb.w);
    *(bf16x8*)(out + (size_t)row * 2048 + tid * 8) = o;
}

// ------------- fp32 [K][N] -> bf16 [N][K] transposed convert -----------------
__global__ __launch_bounds__(256) void wtrans(const float* __restrict__ W,
                                              BF16* __restrict__ Wt,
                                              int K, int N) {
    __shared__ BF16 tile[32][33];
    const int n0 = blockIdx.x * 32, k0 = blockIdx.y * 32;
    const int tx = threadIdx.x, ty = threadIdx.y;
    #pragma unroll
    for (int i = 0; i < 4; i++)
        tile[ty + 8 * i][tx] = (BF16)W[(size_t)(k0 + ty + 8 * i) * N + n0 + tx];
    __syncthreads();
    #pragma unroll
    for (int i = 0; i < 4; i++)
        Wt[(size_t)(n0 + ty + 8 * i) * K + k0 + tx] = tile[tx][ty + 8 * i];
}

// --------- V slice of qkv (bf16 [B,T,3C]) -> vT bf16 [B*H][128][2048] ---------
__global__ __launch_bounds__(256) void vtrans(const BF16* __restrict__ qkv,
                                              BF16* __restrict__ vT) {
    __shared__ BF16 tile[32][33];
    const int t0 = blockIdx.x * 32, d0 = blockIdx.y * 32, bh = blockIdx.z;
    const int b = bh >> 4, h = bh & 15;
    const int tx = threadIdx.x, ty = threadIdx.y;
    const BF16* src = qkv + (size_t)b * 2048 * 6144 + 4096 + h * 128;
    #pragma unroll
    for (int i = 0; i < 4; i++)
        tile[ty + 8 * i][tx] = src[(size_t)(t0 + ty + 8 * i) * 6144 + d0 + tx];
    __syncthreads();
    BF16* dst = vT + (size_t)bh * 128 * 2048;
    #pragma unroll
    for (int i = 0; i < 4; i++)
        dst[(size_t)(d0 + ty + 8 * i) * 2048 + t0 + tx] = tile[tx][ty + 8 * i];
}

// ================== 8-phase-style GEMM: C = A[M,K] * Bt[N,K]^T ================
// BK=32, 4-deep LDS rotation, tile t stages tile t+3, counted vmcnt (never 0
// in main loop), XOR slot swizzle (2-way = free), setprio around MFMA,
// bijective XCD block swizzle. MODE 0: bf16; 1: gelu->bf16; 2: f32 resid+acc.
#define STAGE_A(SB, TS) do { \
    gld_lds16(gA + (size_t)(TS) * 32, lA + (SB) * ABUF); \
    if (LA == 2) gld_lds16(gA + (size_t)(TS) * 32 + (size_t)128 * K, \
                           lA + (SB) * ABUF + 4096); \
} while (0)

#define STAGE_B(SB, TS) do { \
    gld_lds16(gB + (size_t)(TS) * 32, lB + (SB) * BBUF); \
    if (LB == 2) gld_lds16(gB + (size_t)(TS) * 32 + (size_t)128 * K, \
                           lB + (SB) * BBUF + 4096); \
} while (0)

#define TILE(BUF, TS, DS, VM) do { \
    bf16x8 af[MR], bf[NPN]; \
    _Pragma("unroll") \
    for (int m = 0; m < MR; ++m) \
        af[m] = *(const bf16x8*)&As[(BUF) * ABUF + aoff + m * 512]; \
    _Pragma("unroll") \
    for (int n = 0; n < NPN; ++n) \
        bf[n] = *(const bf16x8*)&Bs[(BUF) * BBUF + boff + n * 512]; \
    if (DS) STAGE_A(((BUF) + 3) & 3, TS); \
    if (NPH == 1) { if (DS) STAGE_B(((BUF) + 3) & 3, TS); vmwait<(VM)>(); } \
    barrier_(); \
    __builtin_amdgcn_s_setprio(1); \
    _Pragma("unroll") \
    for (int m = 0; m < MR; ++m) \
      _Pragma("unroll") \
      for (int n = 0; n < NPN; ++n) \
        acc[m][n] = __builtin_amdgcn_mfma_f32_16x16x32_bf16(af[m], bf[n], acc[m][n], 0, 0, 0); \
    __builtin_amdgcn_s_setprio(0); \
    barrier_(); \
    if (NPH == 2) { \
      bf16x8 bf2[NPN]; \
      _Pragma("unroll") \
      for (int n = 0; n < NPN; ++n) \
          bf2[n] = *(const bf16x8*)&Bs[(BUF) * BBUF + boff + (NPN + n) * 512]; \
      if (DS) STAGE_B(((BUF) + 3) & 3, TS); \
      vmwait<(VM)>(); \
      barrier_(); \
      __builtin_amdgcn_s_setprio(1); \
      _Pragma("unroll") \
      for (int m = 0; m < MR; ++m) \
        _Pragma("unroll") \
        for (int n = 0; n < NPN; ++n) \
          acc[m][NPN + n] = __builtin_amdgcn_mfma_f32_16x16x32_bf16(af[m], bf2[n], acc[m][NPN + n], 0, 0, 0); \
      __builtin_amdgcn_s_setprio(0); \
      barrier_(); \
    } \
} while (0)

template <int MODE, int BM, int BN, int WM, int WN>
__global__ __launch_bounds__(512) void gemm8(const BF16* __restrict__ A,
                                             const BF16* __restrict__ Bt,
                                             void* __restrict__ out,
                                             const float* __restrict__ resid,
                                             int M, int N, int K) {
    constexpr int MR  = BM / WM / 16;      // M fragment repeat per wave
    constexpr int NR  = BN / WN / 16;      // N fragment repeat per wave
    constexpr int NPH = (MR * NR) / 16;    // MFMA phases per K-tile (1 or 2)
    constexpr int NPN = NR / NPH;          // n-frags per phase
    constexpr int LA  = BM / 128;          // A stage loads/thread/tile
    constexpr int LB  = BN / 128;
    constexpr int L   = LA + LB;
    constexpr int ABUF = BM * 32;          // elems per A buffer
    constexpr int BBUF = BN * 32;
    (void)M;

    extern __shared__ char smem[];
    BF16* const As = (BF16*)smem;          // [4][ABUF]
    BF16* const Bs = As + 4 * ABUF;        // [4][BBUF]

    const int tid = threadIdx.x, l = tid & 63, w = tid >> 6;
    const int wm = w / WN, wn = w % WN;
    const int g = l >> 4, c = l & 15;
    const int fa = (c >> 1) & 3;           // read-side slot XOR

    const int NBX = N / BN;
    const int cpx = (int)gridDim.x >> 3;   // nwg % 8 == 0 by construction
    const int bid = (int)blockIdx.x;
    const int wg  = (bid & 7) * cpx + (bid >> 3);
    const int m0 = (wg / NBX) * BM, n0 = (wg % NBX) * BN;

    // staging: thread covers LDS bytes tid*16 (+8192 for 2nd load);
    // r = row, slot klog = linear slot XOR'd by ((r>>1)&3) (involution)
    const int r0 = tid >> 2;
    const int klog = (tid & 3) ^ ((r0 >> 1) & 3);
    const BF16* const gA = A  + (size_t)(m0 + r0) * K + klog * 8;
    const BF16* const gB = Bt + (size_t)(n0 + r0) * K + klog * 8;
    BF16* const lA = As + w * 512;         // wave-uniform LDS dest
    BF16* const lB = Bs + w * 512;

    const int aoff = (wm * (BM / WM) + c) * 32 + ((g ^ fa) << 3);
    const int boff = (wn * (BN / WN) + c) * 32 + ((g ^ fa) << 3);

    f32x4 acc[MR][NR] = {};

    // prologue: stage tiles 0,1,2; wait tile 0 (2L still in flight)
    STAGE_A(0, 0); STAGE_B(0, 0);
    STAGE_A(1, 1); STAGE_B(1, 1);
    STAGE_A(2, 2); STAGE_B(2, 2);
    vmwait<2 * L>();
    barrier_();

    const int NT = K >> 5;                 // K-tiles (K % 128 == 0, NT >= 8)
    for (int t = 0; t < NT - 4; t += 4) {
        TILE(0, t + 3, true, 2 * L);
        TILE(1, t + 4, true, 2 * L);
        TILE(2, t + 5, true, 2 * L);
        TILE(3, t + 6, true, 2 * L);
    }
    TILE(0, NT - 1, true, 2 * L);
    TILE(1, 0, false, L);
    TILE(2, 0, false, 0);
    TILE(3, 0, false, -1);

    #pragma unroll
    for (int mi = 0; mi < MR; mi++)
      #pragma unroll
      for (int ni = 0; ni < NR; ni++)
        #pragma unroll
        for (int j = 0; j < 4; j++) {
            const int row = m0 + wm * (BM / WM) + mi * 16 + g * 4 + j;
            const int col = n0 + wn * (BN / WN) + ni * 16 + c;
            const float v = acc[mi][ni][j];
            const size_t idx = (size_t)row * N + col;
            if (MODE == 0) {
                ((BF16*)out)[idx] = (BF16)v;
            } else if (MODE == 1) {
                const float t2 = v + 0.044715f * v * v * v;
                const float s = 1.0f / (1.0f + __expf(-1.5957691216057308f * t2));
                ((BF16*)out)[idx] = (BF16)(v * s);
            } else {
                ((float*)out)[idx] = resid[idx] + v;
            }
        }
}

// ------------------------- causal flash attention ----------------------------
// grid (32, B*H), 4 waves, QBLK=64 (16 q rows/wave), KBLK=64, D=128.
__global__ __launch_bounds__(256) void attn(const BF16* __restrict__ qkv,
                                            const BF16* __restrict__ vT,
                                            const float* __restrict__ x,
                                            float* __restrict__ x2) {
    __shared__ BF16 Ks[64 * 128];      // [key][d]   row = 256 B, swizzled
    __shared__ BF16 Vs[128 * 64];      // [d][key]   row = 128 B, swizzled
    __shared__ BF16 Ps[4][16 * 72];    // per-wave P [q][key], pad 64->72
    const int tid = threadIdx.x, l = tid & 63, w = tid >> 6;
    const int g = l >> 4, c = l & 15;
    const int qb = 31 - (int)blockIdx.x, bh = blockIdx.y;
    const int b = bh >> 4, h = bh & 15;
    const int q0 = qb * 64;
    const int xr = (c & 7) << 4;       // read-side XOR (row = *16 + c)

    const BF16* qbase = qkv + (size_t)b * 2048 * 6144 + h * 128;
    const char* kbase = (const char*)(qbase + 2048);
    const char* vbase = (const char*)(vT + (size_t)bh * 128 * 2048);

    bf16x8 qf[4];
    {
        const BF16* qrow = qbase + (size_t)(q0 + w * 16 + c) * 6144 + g * 8;
        #pragma unroll
        for (int kc = 0; kc < 4; kc++) qf[kc] = *(const bf16x8*)(qrow + kc * 32);
    }

    float m[4]    = {-1e30f, -1e30f, -1e30f, -1e30f};
    float lsum[4] = {0.f, 0.f, 0.f, 0.f};
    f32x4 O[8] = {};
    const float scale = 0.08838834764831845f;  // 1/sqrt(128)

    for (int kt = 0; kt <= qb; ++kt) {
        const int k0 = kt * 64;
        __syncthreads();
        #pragma unroll
        for (int s = 0; s < 4; ++s) {
            const int rK = (w * 4 + s) * 4 + (l >> 4);
            const int cK = ((l & 15) * 16) ^ ((rK & 7) << 4);
            gld_lds16(kbase + (size_t)(k0 + rK) * 12288 + cK,
                      &Ks[(w * 4 + s) * 512]);
            const int rV = (w * 4 + s) * 8 + (l >> 3);
            const int cV = ((l & 7) * 16) ^ ((rV & 7) << 4);
            gld_lds16(vbase + (size_t)rV * 4096 + (size_t)k0 * 2 + cV,
                      &Vs[(w * 4 + s) * 512]);
        }
        __syncthreads();

        f32x4 s4[4] = {};
        #pragma unroll
        for (int ni = 0; ni < 4; ni++)
            #pragma unroll
            for (int kc = 0; kc < 4; kc++) {
                const bf16x8 kf = *(const bf16x8*)((const char*)Ks +
                    (ni * 16 + c) * 256 + ((kc * 64 + g * 16) ^ xr));
                s4[ni] = __builtin_amdgcn_mfma_f32_16x16x32_bf16(
                    qf[kc], kf, s4[ni], 0, 0, 0);
            }

        const bool maskt = (kt == qb);
        float sv[4][4];
        #pragma unroll
        for (int ni = 0; ni < 4; ni++)
            #pragma unroll
            for (int j = 0; j < 4; j++) {
                const float v = s4[ni][j] * scale;
                sv[ni][j] = (!maskt || (ni * 16 + c <= w * 16 + g * 4 + j))
                          ? v : -1e30f;
            }

        float sf[4];
        #pragma unroll
        for (int j = 0; j < 4; j++) {
            float tm = fmaxf(fmaxf(sv[0][j], sv[1][j]), fmaxf(sv[2][j], sv[3][j]));
            tm = fmaxf(tm, __shfl_xor(tm, 1));
            tm = fmaxf(tm, __shfl_xor(tm, 2));
            tm = fmaxf(tm, __shfl_xor(tm, 4));
            tm = fmaxf(tm, __shfl_xor(tm, 8));
            const float mn = fmaxf(m[j], tm);
            sf[j] = __expf(m[j] - mn);
            m[j] = mn;
        }

        float rs[4] = {0.f, 0.f, 0.f, 0.f};
        #pragma unroll
        for (int ni = 0; ni < 4; ni++)
            #pragma unroll
            for (int j = 0; j < 4; j++) {
                const float p = __expf(sv[ni][j] - m[j]);
                rs[j] += p;
                Ps[w][(g * 4 + j) * 72 + ni * 16 + c] = (BF16)p;
            }
        #pragma unroll
        for (int j = 0; j < 4; j++) {
            float t = rs[j];
            t += __shfl_xor(t, 1);
            t += __shfl_xor(t, 2);
            t += __shfl_xor(t, 4);
            t += __shfl_xor(t, 8);
            lsum[j] = lsum[j] * sf[j] + t;
        }
        #pragma unroll
        for (int dn = 0; dn < 8; dn++)
            #pragma unroll
            for (int j = 0; j < 4; j++) O[dn][j] *= sf[j];

        bf16x8 pa[2];
        #pragma unroll
        for (int ks = 0; ks < 2; ks++)
            pa[ks] = *(const bf16x8*)((const char*)Ps[w] +
                         c * 144 + ks * 64 + g * 16);
        #pragma unroll
        for (int dn = 0; dn < 8; dn++)
            #pragma unroll
            for (int ks = 0; ks < 2; ks++) {
                const bf16x8 vf = *(const bf16x8*)((const char*)Vs +
                    (dn * 16 + c) * 128 + ((ks * 64 + g * 16) ^ xr));
                O[dn] = __builtin_amdgcn_mfma_f32_16x16x32_bf16(
                    pa[ks], vf, O[dn], 0, 0, 0);
            }
    }

    float inv[4];
    #pragma unroll
    for (int j = 0; j < 4; j++) inv[j] = 1.0f / lsum[j];
    #pragma unroll
    for (int dn = 0; dn < 8; dn++)
        #pragma unroll
        for (int j = 0; j < 4; j++) {
            const int t   = q0 + w * 16 + g * 4 + j;
            const int col = h * 128 + dn * 16 + c;
            const size_t idx = ((size_t)b * 2048 + t) * 2048 + col;
            x2[idx] = x[idx] + O[dn][j] * inv[j];
        }
}

// -----------------------------------------------------------------------------
extern "C" void kernel_launch(void* const* d_in, const int* in_sizes, int n_in,
                              void* d_out, int out_size, void* d_ws, size_t ws_size,
                              hipStream_t stream) {
    const float* x     = (const float*)d_in[0];
    const float* w_qkv = (const float*)d_in[1];
    const float* w1    = (const float*)d_in[2];
    const float* w2    = (const float*)d_in[3];
    const float* ln_w  = (const float*)d_in[4];
    float* out = (float*)d_out;

    char* ws = (char*)d_ws;
    BF16* h_buf = (BF16*)ws;  ws += (size_t)4096 * 2048 * 2;
    BF16* qkvb  = (BF16*)ws;  ws += (size_t)4096 * 6144 * 2;
    BF16* vTb   = (BF16*)ws;  ws += (size_t)32 * 128 * 2048 * 2;
    BF16* wqkvT = (BF16*)ws;  ws += (size_t)6144 * 2048 * 2;
    BF16* w1T   = (BF16*)ws;  ws += (size_t)8192 * 2048 * 2;
    BF16* w2T   = (BF16*)ws;  ws += (size_t)2048 * 8192 * 2;
    BF16* mlp1  = (BF16*)ws;  ws += (size_t)4096 * 8192 * 2;

    hipFuncSetAttribute((const void*)&gemm8<0, 256, 256, 2, 4>,
                        hipFuncAttributeMaxDynamicSharedMemorySize, 131072);
    hipFuncSetAttribute((const void*)&gemm8<1, 256, 256, 2, 4>,
                        hipFuncAttributeMaxDynamicSharedMemorySize, 131072);
    hipFuncSetAttribute((const void*)&gemm8<2, 256, 128, 4, 2>,
                        hipFuncAttributeMaxDynamicSharedMemorySize, 98304);

    // ---- attention branch ----
    lnorm<<<4096, 256, 0, stream>>>(x, ln_w, h_buf);
    wtrans<<<dim3(192, 64), dim3(32, 8), 0, stream>>>(w_qkv, wqkvT, 2048, 6144);
    gemm8<0, 256, 256, 2, 4><<<384, 512, 131072, stream>>>(
        h_buf, wqkvT, qkvb, nullptr, 4096, 6144, 2048);
    vtrans<<<dim3(64, 4, 32), dim3(32, 8), 0, stream>>>(qkvb, vTb);
    attn<<<dim3(32, 32), 256, 0, stream>>>(qkvb, vTb, x, out);  // out = x2

    // ---- MLP branch ----
    lnorm<<<4096, 256, 0, stream>>>(out, ln_w, h_buf);
    wtrans<<<dim3(256, 64), dim3(32, 8), 0, stream>>>(w1, w1T, 2048, 8192);
    gemm8<1, 256, 256, 2, 4><<<512, 512, 131072, stream>>>(
        h_buf, w1T, mlp1, nullptr, 4096, 8192, 2048);
    wtrans<<<dim3(64, 256), dim3(32, 8), 0, stream>>>(w2, w2T, 8192, 2048);
    gemm8<2, 256, 128, 4, 2><<<256, 512, 98304, stream>>>(
        mlp1, w2T, out, out, 4096, 2048, 8192);
}

// Round 4
// 556.040 us; speedup vs baseline: 1.5133x; 1.1584x over previous
//
#include <hip/hip_runtime.h>
#include <hip/hip_bf16.h>
#include <math.h>

typedef __bf16 BF16;
typedef __attribute__((ext_vector_type(8))) __bf16 bf16x8;
typedef __attribute__((ext_vector_type(4))) float f32x4;

__device__ __forceinline__ void gld_lds16(const void* g, void* l) {
    __builtin_amdgcn_global_load_lds(
        (__attribute__((address_space(1))) void*)(const void*)g,
        (__attribute__((address_space(3))) void*)l, 16, 0, 0);
}

template <int N> __device__ __forceinline__ void vmwait() {
    if constexpr (N == 0) asm volatile("s_waitcnt vmcnt(0)" ::: "memory");
    else if constexpr (N == 2) asm volatile("s_waitcnt vmcnt(2)" ::: "memory");
    else if constexpr (N == 3) asm volatile("s_waitcnt vmcnt(3)" ::: "memory");
    else if constexpr (N == 4) asm volatile("s_waitcnt vmcnt(4)" ::: "memory");
    else if constexpr (N == 6) asm volatile("s_waitcnt vmcnt(6)" ::: "memory");
    else if constexpr (N == 8) asm volatile("s_waitcnt vmcnt(8)" ::: "memory");
}

__device__ __forceinline__ void barrier_() {
    asm volatile("" ::: "memory");
    __builtin_amdgcn_s_barrier();
    asm volatile("" ::: "memory");
}

// ---------------- LayerNorm (fp32 in -> bf16 out), row = 2048 ----------------
__global__ __launch_bounds__(256) void lnorm(const float* __restrict__ x,
                                             const float* __restrict__ w,
                                             BF16* __restrict__ out) {
    const int row = blockIdx.x, tid = threadIdx.x;
    const float* xr = x + (size_t)row * 2048;
    float4 a = *(const float4*)(xr + tid * 8);
    float4 b = *(const float4*)(xr + tid * 8 + 4);
    float s1 = a.x + a.y + a.z + a.w + b.x + b.y + b.z + b.w;
    float s2 = a.x*a.x + a.y*a.y + a.z*a.z + a.w*a.w +
               b.x*b.x + b.y*b.y + b.z*b.z + b.w*b.w;
    #pragma unroll
    for (int off = 32; off; off >>= 1) {
        s1 += __shfl_xor(s1, off);
        s2 += __shfl_xor(s2, off);
    }
    __shared__ float red[8];
    const int l = tid & 63, wv = tid >> 6;
    if (l == 0) { red[wv] = s1; red[4 + wv] = s2; }
    __syncthreads();
    s1 = red[0] + red[1] + red[2] + red[3];
    s2 = red[4] + red[5] + red[6] + red[7];
    const float mean = s1 * (1.0f / 2048.0f);
    const float var  = s2 * (1.0f / 2048.0f) - mean * mean;
    const float rstd = rsqrtf(var + 1e-5f);
    float4 wa = *(const float4*)(w + tid * 8);
    float4 wb = *(const float4*)(w + tid * 8 + 4);
    bf16x8 o;
    o[0] = (BF16)((a.x - mean) * rstd * wa.x);
    o[1] = (BF16)((a.y - mean) * rstd * wa.y);
    o[2] = (BF16)((a.z - mean) * rstd * wa.z);
    o[3] = (BF16)((a.w - mean) * rstd * wa.w);
    o[4] = (BF16)((b.x - mean) * rstd * wb.x);
    o[5] = (BF16)((b.y - mean) * rstd * wb.y);
    o[6] = (BF16)((b.z - mean) * rstd * wb.z);
    o[7] = (BF16)((b.w - mean) * rstd * wb.w);
    *(bf16x8*)(out + (size_t)row * 2048 + tid * 8) = o;
}

// ------------- fp32 [K][N] -> bf16 [N][K] transposed convert -----------------
__global__ __launch_bounds__(256) void wtrans(const float* __restrict__ W,
                                              BF16* __restrict__ Wt,
                                              int K, int N) {
    __shared__ BF16 tile[32][33];
    const int n0 = blockIdx.x * 32, k0 = blockIdx.y * 32;
    const int tx = threadIdx.x, ty = threadIdx.y;
    #pragma unroll
    for (int i = 0; i < 4; i++)
        tile[ty + 8 * i][tx] = (BF16)W[(size_t)(k0 + ty + 8 * i) * N + n0 + tx];
    __syncthreads();
    #pragma unroll
    for (int i = 0; i < 4; i++)
        Wt[(size_t)(n0 + ty + 8 * i) * K + k0 + tx] = tile[tx][ty + 8 * i];
}

// --------- V slice of qkv (bf16 [B,T,3C]) -> vT bf16 [B*H][128][2048] ---------
__global__ __launch_bounds__(256) void vtrans(const BF16* __restrict__ qkv,
                                              BF16* __restrict__ vT) {
    __shared__ BF16 tile[32][33];
    const int t0 = blockIdx.x * 32, d0 = blockIdx.y * 32, bh = blockIdx.z;
    const int b = bh >> 4, h = bh & 15;
    const int tx = threadIdx.x, ty = threadIdx.y;
    const BF16* src = qkv + (size_t)b * 2048 * 6144 + 4096 + h * 128;
    #pragma unroll
    for (int i = 0; i < 4; i++)
        tile[ty + 8 * i][tx] = src[(size_t)(t0 + ty + 8 * i) * 6144 + d0 + tx];
    __syncthreads();
    BF16* dst = vT + (size_t)bh * 128 * 2048;
    #pragma unroll
    for (int i = 0; i < 4; i++)
        dst[(size_t)(d0 + ty + 8 * i) * 2048 + t0 + tx] = tile[tx][ty + 8 * i];
}

// ================== 8-phase-style GEMM: C = A[M,K] * Bt[N,K]^T ================
#define STAGE_A(SB, TS) do { \
    gld_lds16(gA + (size_t)(TS) * 32, lA + (SB) * ABUF); \
    if (LA == 2) gld_lds16(gA + (size_t)(TS) * 32 + (size_t)128 * K, \
                           lA + (SB) * ABUF + 4096); \
} while (0)

#define STAGE_B(SB, TS) do { \
    gld_lds16(gB + (size_t)(TS) * 32, lB + (SB) * BBUF); \
    if (LB == 2) gld_lds16(gB + (size_t)(TS) * 32 + (size_t)128 * K, \
                           lB + (SB) * BBUF + 4096); \
} while (0)

#define TILE(BUF, TS, DS, VM) do { \
    bf16x8 af[MR], bf[NPN]; \
    _Pragma("unroll") \
    for (int m = 0; m < MR; ++m) \
        af[m] = *(const bf16x8*)&As[(BUF) * ABUF + aoff + m * 512]; \
    _Pragma("unroll") \
    for (int n = 0; n < NPN; ++n) \
        bf[n] = *(const bf16x8*)&Bs[(BUF) * BBUF + boff + n * 512]; \
    if (DS) STAGE_A(((BUF) + 3) & 3, TS); \
    if (NPH == 1) { if (DS) STAGE_B(((BUF) + 3) & 3, TS); vmwait<(VM)>(); } \
    barrier_(); \
    __builtin_amdgcn_s_setprio(1); \
    _Pragma("unroll") \
    for (int m = 0; m < MR; ++m) \
      _Pragma("unroll") \
      for (int n = 0; n < NPN; ++n) \
        acc[m][n] = __builtin_amdgcn_mfma_f32_16x16x32_bf16(af[m], bf[n], acc[m][n], 0, 0, 0); \
    __builtin_amdgcn_s_setprio(0); \
    barrier_(); \
    if (NPH == 2) { \
      bf16x8 bf2[NPN]; \
      _Pragma("unroll") \
      for (int n = 0; n < NPN; ++n) \
          bf2[n] = *(const bf16x8*)&Bs[(BUF) * BBUF + boff + (NPN + n) * 512]; \
      if (DS) STAGE_B(((BUF) + 3) & 3, TS); \
      vmwait<(VM)>(); \
      barrier_(); \
      __builtin_amdgcn_s_setprio(1); \
      _Pragma("unroll") \
      for (int m = 0; m < MR; ++m) \
        _Pragma("unroll") \
        for (int n = 0; n < NPN; ++n) \
          acc[m][NPN + n] = __builtin_amdgcn_mfma_f32_16x16x32_bf16(af[m], bf2[n], acc[m][NPN + n], 0, 0, 0); \
      __builtin_amdgcn_s_setprio(0); \
      barrier_(); \
    } \
} while (0)

template <int MODE, int BM, int BN, int WM, int WN>
__global__ __launch_bounds__(512) void gemm8(const BF16* __restrict__ A,
                                             const BF16* __restrict__ Bt,
                                             void* __restrict__ out,
                                             const float* __restrict__ resid,
                                             int M, int N, int K) {
    constexpr int MR  = BM / WM / 16;
    constexpr int NR  = BN / WN / 16;
    constexpr int NPH = (MR * NR) / 16;
    constexpr int NPN = NR / NPH;
    constexpr int LA  = BM / 128;
    constexpr int LB  = BN / 128;
    constexpr int L   = LA + LB;
    constexpr int ABUF = BM * 32;
    constexpr int BBUF = BN * 32;
    (void)M;

    extern __shared__ char smem[];
    BF16* const As = (BF16*)smem;
    BF16* const Bs = As + 4 * ABUF;

    const int tid = threadIdx.x, l = tid & 63, w = tid >> 6;
    const int wm = w / WN, wn = w % WN;
    const int g = l >> 4, c = l & 15;
    const int fa = (c >> 1) & 3;

    const int NBX = N / BN;
    const int cpx = (int)gridDim.x >> 3;
    const int bid = (int)blockIdx.x;
    const int wg  = (bid & 7) * cpx + (bid >> 3);
    const int m0 = (wg / NBX) * BM, n0 = (wg % NBX) * BN;

    const int r0 = tid >> 2;
    const int klog = (tid & 3) ^ ((r0 >> 1) & 3);
    const BF16* const gA = A  + (size_t)(m0 + r0) * K + klog * 8;
    const BF16* const gB = Bt + (size_t)(n0 + r0) * K + klog * 8;
    BF16* const lA = As + w * 512;
    BF16* const lB = Bs + w * 512;

    const int aoff = (wm * (BM / WM) + c) * 32 + ((g ^ fa) << 3);
    const int boff = (wn * (BN / WN) + c) * 32 + ((g ^ fa) << 3);

    f32x4 acc[MR][NR] = {};

    STAGE_A(0, 0); STAGE_B(0, 0);
    STAGE_A(1, 1); STAGE_B(1, 1);
    STAGE_A(2, 2); STAGE_B(2, 2);
    vmwait<2 * L>();
    barrier_();

    const int NT = K >> 5;
    for (int t = 0; t < NT - 4; t += 4) {
        TILE(0, t + 3, true, 2 * L);
        TILE(1, t + 4, true, 2 * L);
        TILE(2, t + 5, true, 2 * L);
        TILE(3, t + 6, true, 2 * L);
    }
    TILE(0, NT - 1, true, 2 * L);
    TILE(1, 0, false, L);
    TILE(2, 0, false, 0);
    TILE(3, 0, false, -1);

    #pragma unroll
    for (int mi = 0; mi < MR; mi++)
      #pragma unroll
      for (int ni = 0; ni < NR; ni++)
        #pragma unroll
        for (int j = 0; j < 4; j++) {
            const int row = m0 + wm * (BM / WM) + mi * 16 + g * 4 + j;
            const int col = n0 + wn * (BN / WN) + ni * 16 + c;
            const float v = acc[mi][ni][j];
            const size_t idx = (size_t)row * N + col;
            if (MODE == 0) {
                ((BF16*)out)[idx] = (BF16)v;
            } else if (MODE == 1) {
                const float t2 = v + 0.044715f * v * v * v;
                const float s = 1.0f / (1.0f + __expf(-1.5957691216057308f * t2));
                ((BF16*)out)[idx] = (BF16)(v * s);
            } else {
                ((float*)out)[idx] = resid[idx] + v;
            }
        }
}

// ------------------------- causal flash attention ----------------------------
// 512 uniform blocks: block = (pair, bh), processes qb=pair then qb=31-pair
// (exactly 33 K/V-tiles each). Double-buffered K/V staging, counted vmcnt(8).
// XCD-chunked block mapping: 64 consecutive wg per XCD -> 4 bh per XCD.
__global__ __launch_bounds__(256) void attn(const BF16* __restrict__ qkv,
                                            const BF16* __restrict__ vT,
                                            const float* __restrict__ x,
                                            float* __restrict__ x2) {
    __shared__ BF16 Ks[2][64 * 128];   // [key][d], swizzled rows (256 B)
    __shared__ BF16 Vs[2][128 * 64];   // [d][key], swizzled rows (128 B)
    __shared__ BF16 Ps[4][16 * 72];    // per-wave P [q][key], pad 64->72
    const int tid = threadIdx.x, l = tid & 63, w = tid >> 6;
    const int g = l >> 4, c = l & 15;
    const int bid = (int)blockIdx.x;
    const int wg = (bid & 7) * 64 + (bid >> 3);   // XCD chunking
    const int pair = wg & 15, bh = wg >> 4;
    const int b = bh >> 4, h = bh & 15;
    const int xr = (c & 7) << 4;

    const BF16* qbase = qkv + (size_t)b * 2048 * 6144 + h * 128;
    const char* kbase = (const char*)(qbase + 2048);
    const char* vbase = (const char*)(vT + (size_t)bh * 128 * 2048);

    auto STAGE = [&](int bb, int k0) {
        #pragma unroll
        for (int s = 0; s < 4; ++s) {
            const int rK = (w * 4 + s) * 4 + (l >> 4);
            const int cK = ((l & 15) * 16) ^ ((rK & 7) << 4);
            gld_lds16(kbase + (size_t)(k0 + rK) * 12288 + cK,
                      &Ks[bb][(w * 4 + s) * 512]);
            const int rV = (w * 4 + s) * 8 + (l >> 3);
            const int cV = ((l & 7) * 16) ^ ((rV & 7) << 4);
            gld_lds16(vbase + (size_t)rV * 4096 + (size_t)k0 * 2 + cV,
                      &Vs[bb][(w * 4 + s) * 512]);
        }
    };

    const float scale = 0.08838834764831845f;  // 1/sqrt(128)

    #pragma unroll 1
    for (int seg = 0; seg < 2; ++seg) {
        const int qb = seg ? 31 - pair : pair;
        const int q0 = qb * 64;

        bf16x8 qf[4];
        {
            const BF16* qrow = qbase + (size_t)(q0 + w * 16 + c) * 6144 + g * 8;
            #pragma unroll
            for (int kc = 0; kc < 4; kc++)
                qf[kc] = *(const bf16x8*)(qrow + kc * 32);
        }
        float m[4]    = {-1e30f, -1e30f, -1e30f, -1e30f};
        float lsum[4] = {0.f, 0.f, 0.f, 0.f};
        f32x4 O[8] = {};

        STAGE(0, 0);
        #pragma unroll 1
        for (int kt = 0; kt <= qb; ++kt) {
            if (kt < qb) { STAGE((kt + 1) & 1, (kt + 1) * 64); vmwait<8>(); }
            else vmwait<0>();
            barrier_();
            const char* KsB = (const char*)Ks[kt & 1];
            const char* VsB = (const char*)Vs[kt & 1];

            f32x4 s4[4] = {};
            #pragma unroll
            for (int ni = 0; ni < 4; ni++)
                #pragma unroll
                for (int kc = 0; kc < 4; kc++) {
                    const bf16x8 kf = *(const bf16x8*)(KsB +
                        (ni * 16 + c) * 256 + ((kc * 64 + g * 16) ^ xr));
                    s4[ni] = __builtin_amdgcn_mfma_f32_16x16x32_bf16(
                        qf[kc], kf, s4[ni], 0, 0, 0);
                }

            const bool maskt = (kt == qb);
            float sv[4][4];
            #pragma unroll
            for (int ni = 0; ni < 4; ni++)
                #pragma unroll
                for (int j = 0; j < 4; j++) {
                    const float v = s4[ni][j] * scale;
                    sv[ni][j] = (!maskt || (ni * 16 + c <= w * 16 + g * 4 + j))
                              ? v : -1e30f;
                }

            float sf[4];
            #pragma unroll
            for (int j = 0; j < 4; j++) {
                float tm = fmaxf(fmaxf(sv[0][j], sv[1][j]),
                                 fmaxf(sv[2][j], sv[3][j]));
                tm = fmaxf(tm, __shfl_xor(tm, 1));
                tm = fmaxf(tm, __shfl_xor(tm, 2));
                tm = fmaxf(tm, __shfl_xor(tm, 4));
                tm = fmaxf(tm, __shfl_xor(tm, 8));
                const float mn = fmaxf(m[j], tm);
                sf[j] = __expf(m[j] - mn);
                m[j] = mn;
            }

            float rs[4] = {0.f, 0.f, 0.f, 0.f};
            #pragma unroll
            for (int ni = 0; ni < 4; ni++)
                #pragma unroll
                for (int j = 0; j < 4; j++) {
                    const float p = __expf(sv[ni][j] - m[j]);
                    rs[j] += p;
                    Ps[w][(g * 4 + j) * 72 + ni * 16 + c] = (BF16)p;
                }
            #pragma unroll
            for (int j = 0; j < 4; j++) {
                float t = rs[j];
                t += __shfl_xor(t, 1);
                t += __shfl_xor(t, 2);
                t += __shfl_xor(t, 4);
                t += __shfl_xor(t, 8);
                lsum[j] = lsum[j] * sf[j] + t;
            }
            #pragma unroll
            for (int dn = 0; dn < 8; dn++)
                #pragma unroll
                for (int j = 0; j < 4; j++) O[dn][j] *= sf[j];

            bf16x8 pa[2];
            #pragma unroll
            for (int ks = 0; ks < 2; ks++)
                pa[ks] = *(const bf16x8*)((const char*)Ps[w] +
                             c * 144 + ks * 64 + g * 16);
            #pragma unroll
            for (int dn = 0; dn < 8; dn++)
                #pragma unroll
                for (int ks = 0; ks < 2; ks++) {
                    const bf16x8 vf = *(const bf16x8*)(VsB +
                        (dn * 16 + c) * 128 + ((ks * 64 + g * 16) ^ xr));
                    O[dn] = __builtin_amdgcn_mfma_f32_16x16x32_bf16(
                        pa[ks], vf, O[dn], 0, 0, 0);
                }
            barrier_();
        }

        float inv[4];
        #pragma unroll
        for (int j = 0; j < 4; j++) inv[j] = 1.0f / lsum[j];
        #pragma unroll
        for (int dn = 0; dn < 8; dn++)
            #pragma unroll
            for (int j = 0; j < 4; j++) {
                const int t   = q0 + w * 16 + g * 4 + j;
                const int col = h * 128 + dn * 16 + c;
                const size_t idx = ((size_t)b * 2048 + t) * 2048 + col;
                x2[idx] = x[idx] + O[dn][j] * inv[j];
            }
    }
}

// -----------------------------------------------------------------------------
extern "C" void kernel_launch(void* const* d_in, const int* in_sizes, int n_in,
                              void* d_out, int out_size, void* d_ws, size_t ws_size,
                              hipStream_t stream) {
    const float* x     = (const float*)d_in[0];
    const float* w_qkv = (const float*)d_in[1];
    const float* w1    = (const float*)d_in[2];
    const float* w2    = (const float*)d_in[3];
    const float* ln_w  = (const float*)d_in[4];
    float* out = (float*)d_out;

    char* ws = (char*)d_ws;
    BF16* h_buf = (BF16*)ws;  ws += (size_t)4096 * 2048 * 2;
    BF16* qkvb  = (BF16*)ws;  ws += (size_t)4096 * 6144 * 2;
    BF16* vTb   = (BF16*)ws;  ws += (size_t)32 * 128 * 2048 * 2;
    BF16* wqkvT = (BF16*)ws;  ws += (size_t)6144 * 2048 * 2;
    BF16* w1T   = (BF16*)ws;  ws += (size_t)8192 * 2048 * 2;
    BF16* w2T   = (BF16*)ws;  ws += (size_t)2048 * 8192 * 2;
    BF16* mlp1  = (BF16*)ws;  ws += (size_t)4096 * 8192 * 2;

    hipFuncSetAttribute((const void*)&gemm8<0, 256, 256, 2, 4>,
                        hipFuncAttributeMaxDynamicSharedMemorySize, 131072);
    hipFuncSetAttribute((const void*)&gemm8<1, 256, 256, 2, 4>,
                        hipFuncAttributeMaxDynamicSharedMemorySize, 131072);
    hipFuncSetAttribute((const void*)&gemm8<2, 256, 128, 4, 2>,
                        hipFuncAttributeMaxDynamicSharedMemorySize, 98304);

    // ---- attention branch ----
    lnorm<<<4096, 256, 0, stream>>>(x, ln_w, h_buf);
    wtrans<<<dim3(192, 64), dim3(32, 8), 0, stream>>>(w_qkv, wqkvT, 2048, 6144);
    gemm8<0, 256, 256, 2, 4><<<384, 512, 131072, stream>>>(
        h_buf, wqkvT, qkvb, nullptr, 4096, 6144, 2048);
    vtrans<<<dim3(64, 4, 32), dim3(32, 8), 0, stream>>>(qkvb, vTb);
    attn<<<512, 256, 0, stream>>>(qkvb, vTb, x, out);  // out = x2

    // ---- MLP branch ----
    lnorm<<<4096, 256, 0, stream>>>(out, ln_w, h_buf);
    wtrans<<<dim3(256, 64), dim3(32, 8), 0, stream>>>(w1, w1T, 2048, 8192);
    gemm8<1, 256, 256, 2, 4><<<512, 512, 131072, stream>>>(
        h_buf, w1T, mlp1, nullptr, 4096, 8192, 2048);
    wtrans<<<dim3(64, 256), dim3(32, 8), 0, stream>>>(w2, w2T, 8192, 2048);
    gemm8<2, 256, 128, 4, 2><<<256, 512, 98304, stream>>>(
        mlp1, w2T, out, out, 4096, 2048, 8192);
}